// Round 2
// baseline (273.197 us; speedup 1.0000x reference)
//
#include <hip/hip_runtime.h>

typedef __attribute__((ext_vector_type(8))) short bf16x8;
typedef __attribute__((ext_vector_type(4))) float f32x4;
typedef unsigned short u16;

#define MFMA16(a, b, c) __builtin_amdgcn_mfma_f32_16x16x32_bf16(a, b, c, 0, 0, 0)

__device__ __forceinline__ u16 f2b(float f) {
  union { float f; unsigned u; } a; a.f = f;
  return (u16)((a.u + 0x7FFFu + ((a.u >> 16) & 1u)) >> 16);
}

// ---------------- converts ----------------
__global__ __launch_bounds__(256) void conv_bf16(const float* __restrict__ in,
                                                 u16* __restrict__ out, int n4) {
  int i = blockIdx.x * 256 + threadIdx.x;
  if (i >= n4) return;
  const float4 v = *(const float4*)(in + (size_t)i * 4);
  ushort4 o;
  o.x = f2b(v.x); o.y = f2b(v.y); o.z = f2b(v.z); o.w = f2b(v.w);
  *(ushort4*)(out + (size_t)i * 4) = o;
}

// k_cache [16][1536][64] f32 -> k_full [16][2048][64] bf16 (rows 0..1535)
__global__ __launch_bounds__(256) void kcache_copy(const float* __restrict__ kc,
                                                   u16* __restrict__ kf) {
  int i = blockIdx.x * 256 + threadIdx.x;  // 393216 chunks of 4
  int bh = i / 24576, r = i - bh * 24576;
  const float4 v = *(const float4*)(kc + (size_t)bh * 98304 + (size_t)r * 4);
  ushort4 o;
  o.x = f2b(v.x); o.y = f2b(v.y); o.z = f2b(v.z); o.w = f2b(v.w);
  *(ushort4*)(kf + (size_t)bh * 131072 + (size_t)r * 4) = o;
}

// v_cache [16][1536][64] f32 -> vT [16][64][2048] bf16 (cols 0..1535), LDS-tiled transpose
__global__ __launch_bounds__(256) void vcache_transpose(const float* __restrict__ vc,
                                                        u16* __restrict__ vT) {
  __shared__ float tile[64][65];
  const int bh = blockIdx.y, kt = blockIdx.x;
  const float* src = vc + ((size_t)bh * 1536 + (size_t)kt * 64) * 64;
  const int t = threadIdx.x;
#pragma unroll
  for (int j = 0; j < 4; j++) {
    int e = t + j * 256;            // 0..1023 chunks of 4
    int r = e >> 4, c = (e & 15) * 4;
    float4 v = *(const float4*)(src + (size_t)r * 64 + c);
    tile[r][c] = v.x; tile[r][c + 1] = v.y; tile[r][c + 2] = v.z; tile[r][c + 3] = v.w;
  }
  __syncthreads();
  int d = t >> 2, kv0 = (t & 3) * 16;
  u16* dst = vT + ((size_t)bh * 64 + d) * 2048 + (size_t)kt * 64 + kv0;
#pragma unroll
  for (int i = 0; i < 16; i++) dst[i] = f2b(tile[kv0 + i][d]);
}

// ---------------- GEMM: C[M][N] = A[M][K] * B[N][K]^T  (bf16 in, f32 out) ----------------
__global__ __launch_bounds__(256) void gemm_bt(const u16* __restrict__ A,
                                               const u16* __restrict__ B,
                                               float* __restrict__ C,
                                               int M, int N, int K) {
  __shared__ __attribute__((aligned(16))) u16 As[4096];  // 128 x 32
  __shared__ __attribute__((aligned(16))) u16 Bs[4096];
  const int t = threadIdx.x;
  const int lane = t & 63, wv = t >> 6;
  const int wr = (wv >> 1) * 64, wc = (wv & 1) * 64;
  const int g = lane >> 4, cc = lane & 15;
  const size_t row0 = (size_t)blockIdx.x * 128, col0 = (size_t)blockIdx.y * 128;

  f32x4 acc[4][4] = {};

  const int sr = t >> 2, sce = (t & 3) * 8;
  const u16* a0 = A + (row0 + sr) * K + sce;
  const u16* a1 = A + (row0 + 64 + sr) * K + sce;
  const u16* b0 = B + (col0 + sr) * K + sce;
  const u16* b1 = B + (col0 + 64 + sr) * K + sce;
  u16* ldsA0 = As + wv * 512;
  u16* ldsA1 = As + 2048 + wv * 512;
  u16* ldsB0 = Bs + wv * 512;
  u16* ldsB1 = Bs + 2048 + wv * 512;

  for (int k0 = 0; k0 < K; k0 += 32) {
    __syncthreads();
    __builtin_amdgcn_global_load_lds((const __attribute__((address_space(1))) void*)(a0 + k0),
                                     (__attribute__((address_space(3))) void*)ldsA0, 16, 0, 0);
    __builtin_amdgcn_global_load_lds((const __attribute__((address_space(1))) void*)(a1 + k0),
                                     (__attribute__((address_space(3))) void*)ldsA1, 16, 0, 0);
    __builtin_amdgcn_global_load_lds((const __attribute__((address_space(1))) void*)(b0 + k0),
                                     (__attribute__((address_space(3))) void*)ldsB0, 16, 0, 0);
    __builtin_amdgcn_global_load_lds((const __attribute__((address_space(1))) void*)(b1 + k0),
                                     (__attribute__((address_space(3))) void*)ldsB1, 16, 0, 0);
    __syncthreads();
    bf16x8 av[4], bv[4];
#pragma unroll
    for (int m = 0; m < 4; m++)
      av[m] = *(const bf16x8*)(As + (wr + m * 16 + cc) * 32 + g * 8);
#pragma unroll
    for (int n = 0; n < 4; n++)
      bv[n] = *(const bf16x8*)(Bs + (wc + n * 16 + cc) * 32 + g * 8);
#pragma unroll
    for (int m = 0; m < 4; m++)
#pragma unroll
      for (int n = 0; n < 4; n++)
        acc[m][n] = MFMA16(av[m], bv[n], acc[m][n]);
  }
#pragma unroll
  for (int m = 0; m < 4; m++)
#pragma unroll
    for (int n = 0; n < 4; n++)
#pragma unroll
      for (int r = 0; r < 4; r++)
        C[(row0 + wr + m * 16 + g * 4 + r) * N + (col0 + wc + n * 16 + cc)] = acc[m][n][r];
}

// ---------------- RoPE + scatter ----------------
// Cqkv [1024][3072] f32. q cols 0..2047, k cols 2048..2559, v cols 2560..3071
__global__ __launch_bounds__(256) void postproc(const float* __restrict__ Cqkv,
                                                const float* __restrict__ fcos,
                                                const float* __restrict__ fsin,
                                                u16* __restrict__ qrope,
                                                u16* __restrict__ kfull,
                                                u16* __restrict__ vT,
                                                float* __restrict__ newk,
                                                float* __restrict__ newv) {
  int idx = blockIdx.x * 256 + threadIdx.x;
  if (idx >= 1024 * 1536) return;
  int m = idx / 1536, p = idx - m * 1536;
  int b = m >> 9, s = m & 511;
  const float* row = Cqkv + (size_t)m * 3072;
  if (p < 1280) {
    bool isq = p < 1024;
    int pk = isq ? p : p - 1024;
    int h = pk >> 5, i = pk & 31;
    int colbase = (isq ? 0 : 2048) + h * 64 + 2 * i;
    float xr = row[colbase], xi = row[colbase + 1];
    float co = fcos[s * 32 + i], si = fsin[s * 32 + i];
    float orr = xr * co - xi * si;
    float oii = xr * si + xi * co;
    if (isq) {
      u16* dst = qrope + (((size_t)(b * 32 + h) * 512 + s) * 64 + 2 * i);
      dst[0] = f2b(orr); dst[1] = f2b(oii);
    } else {
      size_t o0 = ((size_t)(b * 8 + h) * 512 + s) * 64 + 2 * i;
      newk[o0] = orr; newk[o0 + 1] = oii;
      u16* kf = kfull + (((size_t)(b * 8 + h) * 2048 + 1536 + s) * 64 + 2 * i);
      kf[0] = f2b(orr); kf[1] = f2b(oii);
    }
  } else {
    int pv = p - 1280;
    int h = pv >> 5, i = pv & 31;
    float v0 = row[2560 + h * 64 + 2 * i], v1 = row[2560 + h * 64 + 2 * i + 1];
    size_t o0 = ((size_t)(b * 8 + h) * 512 + s) * 64 + 2 * i;
    newv[o0] = v0; newv[o0 + 1] = v1;
    u16* vt = vT + ((size_t)(b * 8 + h) * 64 + 2 * i) * 2048 + 1536 + s;
    vt[0] = f2b(v0); vt[2048] = f2b(v1);
  }
}

// ---------------- flash attention ----------------
// qrope [64bh][512][64] bf16, kfull [16bhkv][2048][64] bf16, vT [16bhkv][64][2048] bf16,
// mask [512][2048] f32, aout [1024][2048] bf16 (b,s, h*64+d)
__global__ __launch_bounds__(256) void attn_kernel(const u16* __restrict__ qrope,
                                                   const u16* __restrict__ kfull,
                                                   const u16* __restrict__ vT,
                                                   const float* __restrict__ mask,
                                                   u16* __restrict__ aout) {
  __shared__ __attribute__((aligned(16))) u16 P_lds[4096];  // 4 waves x 16x64
  const int t = threadIdx.x, lane = t & 63, w = t >> 6;
  const int g = lane >> 4, cc = lane & 15;
  const int qt = blockIdx.x, bh = blockIdx.y;
  const int b = bh >> 5, h = bh & 31;
  const int bhkv = b * 8 + (h >> 2);
  const int s0 = qt * 64 + w * 16;

  bf16x8 qa0, qa1;
  {
    const u16* qb = qrope + ((size_t)bh * 512 + s0 + cc) * 64 + g * 8;
    qa0 = *(const bf16x8*)qb;
    qa1 = *(const bf16x8*)(qb + 32);
  }
  float mrow[4], ssum[4];
  f32x4 o[4] = {};
#pragma unroll
  for (int r = 0; r < 4; r++) { mrow[r] = -1e30f; ssum[r] = 0.0f; }

  u16* Pw = P_lds + w * 1024;
  const u16* kbase = kfull + ((size_t)bhkv * 2048 + cc) * 64 + g * 8;
  const u16* vbase = vT + ((size_t)bhkv * 64 + cc) * 2048 + g * 8;
  const float* mbase = mask + (size_t)(s0 + g * 4) * 2048 + cc;

  for (int j0 = 0; j0 < 2048; j0 += 64) {
    f32x4 sc[4];
#pragma unroll
    for (int jb = 0; jb < 4; jb++) {
      const u16* kp = kbase + (size_t)(j0 + jb * 16) * 64;
      f32x4 z = {0.f, 0.f, 0.f, 0.f};
      z = MFMA16(qa0, *(const bf16x8*)kp, z);
      z = MFMA16(qa1, *(const bf16x8*)(kp + 32), z);
      sc[jb] = z;
    }
    float p[4][4];
#pragma unroll
    for (int r = 0; r < 4; r++) {
#pragma unroll
      for (int jb = 0; jb < 4; jb++)
        p[r][jb] = sc[jb][r] * 0.125f + mbase[(size_t)r * 2048 + j0 + jb * 16];
      float tm = fmaxf(fmaxf(p[r][0], p[r][1]), fmaxf(p[r][2], p[r][3]));
#pragma unroll
      for (int off = 1; off < 16; off <<= 1) tm = fmaxf(tm, __shfl_xor(tm, off, 64));
      float newm = fmaxf(mrow[r], tm);
      float corr = __expf(mrow[r] - newm);
      mrow[r] = newm;
      float ps = 0.f;
#pragma unroll
      for (int jb = 0; jb < 4; jb++) { p[r][jb] = __expf(p[r][jb] - newm); ps += p[r][jb]; }
#pragma unroll
      for (int off = 1; off < 16; off <<= 1) ps += __shfl_xor(ps, off, 64);
      ssum[r] = ssum[r] * corr + ps;
#pragma unroll
      for (int db = 0; db < 4; db++) o[db][r] *= corr;
      const int rowb = (g * 4 + r) * 128;
      const int sw = ((g * 4 + r) & 7) << 4;
#pragma unroll
      for (int jb = 0; jb < 4; jb++)
        Pw[((rowb + (jb * 16 + cc) * 2) ^ sw) >> 1] = f2b(p[r][jb]);
    }
#pragma unroll
    for (int kk = 0; kk < 2; kk++) {
      const bf16x8 pa =
          *(const bf16x8*)(Pw + (((cc * 128 + kk * 64 + g * 16) ^ ((cc & 7) << 4)) >> 1));
#pragma unroll
      for (int db = 0; db < 4; db++) {
        const bf16x8 vb = *(const bf16x8*)(vbase + (size_t)(db * 16) * 2048 + j0 + kk * 32);
        o[db] = MFMA16(pa, vb, o[db]);
      }
    }
  }
#pragma unroll
  for (int r = 0; r < 4; r++) {
    const float inv = 1.0f / ssum[r];
    u16* dst = aout + ((size_t)(b * 512 + s0 + g * 4 + r)) * 2048 + h * 64 + cc;
#pragma unroll
    for (int db = 0; db < 4; db++) dst[db * 16] = f2b(o[db][r] * inv);
  }
}

// ---------------- launch ----------------
extern "C" void kernel_launch(void* const* d_in, const int* in_sizes, int n_in,
                              void* d_out, int out_size, void* d_ws, size_t ws_size,
                              hipStream_t stream) {
  (void)in_sizes; (void)n_in; (void)out_size; (void)ws_size;
  const float* x    = (const float*)d_in[0];
  const float* fcos = (const float*)d_in[1];
  const float* fsin = (const float*)d_in[2];
  const float* kc   = (const float*)d_in[3];
  const float* vc   = (const float*)d_in[4];
  const float* mask = (const float*)d_in[5];
  const float* wq   = (const float*)d_in[6];
  const float* wk   = (const float*)d_in[7];
  const float* wv   = (const float*)d_in[8];
  const float* wo   = (const float*)d_in[9];

  float* out_f = (float*)d_out;                 // [2][512][2048]
  float* newk  = out_f + 2097152;               // [2][8][512][64]
  float* newv  = out_f + 2621440;               // [2][8][512][64]

  u16*   xb    = (u16*)d_ws;                    // 2,097,152
  u16*   wcat  = xb + 2097152;                  // 6,291,456  (wq|wk|wv rows)
  u16*   wob   = wcat + 6291456;                // 4,194,304
  float* Cqkv  = (float*)(wob + 4194304);       // 3,145,728 f32
  u16*   qrope = (u16*)(Cqkv + 3145728);        // 2,097,152
  u16*   kfull = qrope + 2097152;               // 2,097,152
  u16*   vTf   = kfull + 2097152;               // 2,097,152
  u16*   aout  = vTf + 2097152;                 // 2,097,152

  conv_bf16<<<2048, 256, 0, stream>>>(x, xb, 524288);
  conv_bf16<<<4096, 256, 0, stream>>>(wq, wcat, 1048576);
  conv_bf16<<<1024, 256, 0, stream>>>(wk, wcat + 4194304, 262144);
  conv_bf16<<<1024, 256, 0, stream>>>(wv, wcat + 5242880, 262144);
  conv_bf16<<<4096, 256, 0, stream>>>(wo, wob, 1048576);
  kcache_copy<<<1536, 256, 0, stream>>>(kc, kfull);
  vcache_transpose<<<dim3(24, 16), 256, 0, stream>>>(vc, vTf);

  gemm_bt<<<dim3(8, 24), 256, 0, stream>>>(xb, wcat, Cqkv, 1024, 3072, 2048);
  postproc<<<6144, 256, 0, stream>>>(Cqkv, fcos, fsin, qrope, kfull, vTf, newk, newv);
  attn_kernel<<<dim3(8, 64), 256, 0, stream>>>(qrope, kfull, vTf, mask, aout);
  gemm_bt<<<dim3(8, 16), 256, 0, stream>>>(aout, wob, out_f, 1024, 2048, 2048);
}